// Round 12
// baseline (57.230 us; speedup 1.0000x reference)
//
#include <hip/hip_runtime.h>

#define HH 1024
#define WW 1024
#define NIMG 8
#define TROWS 16   // output rows per block
#define SOUT 248   // output px per strip (lanes 1..62 store 4 px each)

__device__ __forceinline__ float med3f(float a, float b, float c) {
    return __builtin_amdgcn_fmed3f(a, b, c);
}
__device__ __forceinline__ float min3f(float a, float b, float c) {
    return fminf(fminf(a, b), c);
}
__device__ __forceinline__ float max3f(float a, float b, float c) {
    return fmaxf(fmaxf(a, b), c);
}

// ranks 3,4 of 5
__device__ __forceinline__ void top2(float a, float b, float c, float d, float e,
                                     float& r3, float& r4) {
    float m3 = med3f(a, b, c);
    float h3 = max3f(a, b, c);
    float s2 = med3f(m3, h3, d);
    float s3 = fmaxf(h3, d);
    r3 = med3f(s2, s3, e);
    r4 = fmaxf(s3, e);
}
// ranks 0,1 of 5
__device__ __forceinline__ void bot2(float a, float b, float c, float d, float e,
                                     float& r0, float& r1) {
    float l3 = min3f(a, b, c);
    float m3 = med3f(a, b, c);
    float s0 = fminf(l3, d);
    float s1 = med3f(l3, m3, d);
    r0 = fminf(s0, e);
    r1 = med3f(s0, s1, e);
}
// ranks 2,3,4 of 5
__device__ __forceinline__ void top3(float a, float b, float c, float d, float e,
                                     float& r2, float& r3, float& r4) {
    float l3 = min3f(a, b, c);
    float m3 = med3f(a, b, c);
    float h3 = max3f(a, b, c);
    float s1 = med3f(l3, m3, d);
    float s2 = med3f(m3, h3, d);
    float s3 = fmaxf(h3, d);
    r2 = med3f(s1, s2, e);
    r3 = med3f(s2, s3, e);
    r4 = fmaxf(s3, e);
}
// ranks 0,1,2 of 5
__device__ __forceinline__ void bot3(float a, float b, float c, float d, float e,
                                     float& r0, float& r1, float& r2) {
    float l3 = min3f(a, b, c);
    float m3 = med3f(a, b, c);
    float h3 = max3f(a, b, c);
    float s0 = fminf(l3, d);
    float s1 = med3f(l3, m3, d);
    float s2 = med3f(m3, h3, d);
    r0 = fminf(s0, e);
    r1 = med3f(s0, s1, e);
    r2 = med3f(s1, s2, e);
}
// ranks 1,2,3 of 5
__device__ __forceinline__ void mid3(float a, float b, float c, float d, float e,
                                     float& r1, float& r2, float& r3) {
    float l3 = min3f(a, b, c);
    float m3 = med3f(a, b, c);
    float h3 = max3f(a, b, c);
    float s0 = fminf(l3, d);
    float s1 = med3f(l3, m3, d);
    float s2 = med3f(m3, h3, d);
    float s3 = fmaxf(h3, d);
    r1 = med3f(s0, s1, e);
    r2 = med3f(s1, s2, e);
    r3 = med3f(s2, s3, e);
}

// load one y-reflect-padded input row, 8 columns x0-2..x0+5.
// lrefl/rrefl: this lane sits at the true image x-edge (x0==0 / x0==1020).
__device__ __forceinline__ void loadrow8(const float* __restrict__ base, int r,
                                         int x0, bool lrefl, bool rrefl,
                                         float (&d)[8]) {
    const int rr = (r < 0) ? -r : (r >= HH ? 2 * HH - 2 - r : r);
    const float* rp = base + (size_t)rr * WW;
    const float4 A = *reinterpret_cast<const float4*>(rp + (lrefl ? x0 : x0 - 4));
    const float4 B = *reinterpret_cast<const float4*>(rp + x0);
    const float4 C = *reinterpret_cast<const float4*>(rp + (rrefl ? x0 : x0 + 4));
    d[0] = lrefl ? B.z : A.z;   // col -2 -> reflect 2
    d[1] = lrefl ? B.y : A.w;   // col -1 -> reflect 1
    d[2] = B.x; d[3] = B.y; d[4] = B.z; d[5] = B.w;
    d[6] = rrefl ? B.z : C.x;   // col 1024 -> reflect 1022
    d[7] = rrefl ? B.y : C.y;   // col 1025 -> reflect 1021
}

// 13-candidate exact median-of-25 network over sorted columns (validated R2-R11)
__device__ __forceinline__ void med4net(const float (&S0)[8], const float (&S1)[8],
                                        const float (&S2)[8], const float (&S3)[8],
                                        const float (&S4)[8], float (&med)[4]) {
    #pragma unroll
    for (int j = 0; j < 4; ++j) {
        float r03, r04, r12, r13, r14, r21, r22, r23, r30, r31, r32, r40, r41;
        top2(S0[j], S0[j+1], S0[j+2], S0[j+3], S0[j+4], r03, r04);
        top3(S1[j], S1[j+1], S1[j+2], S1[j+3], S1[j+4], r12, r13, r14);
        mid3(S2[j], S2[j+1], S2[j+2], S2[j+3], S2[j+4], r21, r22, r23);
        bot3(S3[j], S3[j+1], S3[j+2], S3[j+3], S3[j+4], r30, r31, r32);
        bot2(S4[j], S4[j+1], S4[j+2], S4[j+3], S4[j+4], r40, r41);
        float u = fminf(r40, r31), v = fmaxf(r40, r31);
        float w = fminf(v, r32),  x = fmaxf(v, r32);
        float ps0 = r30, ps1 = u, ps2 = w;
        float ps3 = fminf(x, r41), ps4 = fmaxf(x, r41);
        float q0 = fminf(r21, r03);
        float q1 = med3f(r21, r22, r03);
        float q2 = med3f(r22, r23, r03);
        float t1 = fminf(q1, r04);
        float t2 = med3f(q1, q2, r04);
        float t3 = med3f(q2, r23, r04);
        float t4 = fmaxf(r23, r04);
        float Y0 = fmaxf(ps0, q0);
        float Y1 = fmaxf(ps1, t1);
        float X2 = fminf(ps2, t2), Y2 = fmaxf(ps2, t2);
        float X3 = fminf(ps3, t3);
        float X4 = fminf(ps4, t4);
        float L  = max3f(X2, Y0, r12);
        float M  = med3f(X3, Y1, r13);
        float Hc = min3f(X4, Y2, r14);
        med[j] = med3f(L, M, Hc);
    }
}

// Fused median(reflect) + gaussian(zero-pad), barrier-free 1-wave blocks.
// Block = 1 wave; lane owns 4 px; strip = 248 output px (lanes 0/63 compute
// margin medians only). x-halo via __shfl; y via rolled 10-iteration loop
// over a register ring with explicit shifts (all indices compile-time).
// Grid = 8 img x 5 strips x 64 y-bands = 2560 blocks; img = bid&7 XCD-affine.
__global__ __launch_bounds__(64) void fused_kernel(const float* __restrict__ in,
                                                   const float* __restrict__ sig,
                                                   float* __restrict__ out) {
    const int bi    = blockIdx.x;
    const int img   = bi & 7;
    const int t     = bi >> 3;      // 0..319
    const int strip = t >> 6;       // 0..4
    const int yband = t & 63;       // 0..63
    const int y0    = yband * TROWS;
    const int ox    = (strip < 4) ? SOUT * strip : (WW - SOUT);
    const int lane  = threadIdx.x;  // 0..63
    int x0 = ox - 4 + 4 * lane;
    x0 = x0 < 0 ? 0 : (x0 > WW - 4 ? WW - 4 : x0);
    const bool lrefl   = (x0 == 0);
    const bool rrefl   = (x0 == WW - 4);
    const bool dostore = (lane >= 1) && (lane <= 62);

    const float* base  = in  + (size_t)img * HH * WW;
    float*       obase = out + (size_t)img * HH * WW;

    const float sigma  = sig[0];
    const float inv2s2 = 1.0f / (2.0f * sigma * sigma);
    const float g1 = expf(-1.0f * inv2s2);
    const float g4 = expf(-4.0f * inv2s2);
    const float sn = 1.0f + 2.0f * g1 + 2.0f * g4;
    const float wv[5] = { g4 / sn, g1 / sn, 1.0f / sn, g1 / sn, g4 / sn };

    float R[8][8];     // input-row ring: R[k] = row m0-2+k (static indices)
    #pragma unroll
    for (int k = 0; k < 6; ++k) loadrow8(base, y0 - 4 + k, x0, lrefl, rrefl, R[k]);

    float hr[4][4];    // h-gauss of med rows m0-4..m0-1
    #pragma unroll
    for (int k = 0; k < 4; ++k)
        #pragma unroll
        for (int j = 0; j < 4; ++j) hr[k][j] = 0.f;

    for (int it = 0; it < 10; ++it) {
        const int m0 = y0 - 2 + 2 * it;
        // prefetch rows m0+4, m0+5 (consumed after the shift, next iters)
        if (it <= 8) {
            loadrow8(base, m0 + 4, x0, lrefl, rrefl, R[6]);
            loadrow8(base, m0 + 5, x0, lrefl, rrefl, R[7]);
        }
        // shared sorted4 of rows m0-1..m0+2 (R1..R4)
        float T0[8], T1[8], T2[8], T3[8];
        #pragma unroll
        for (int c = 0; c < 8; ++c) {
            float b = R[1][c], cc = R[2][c], d = R[3][c], e = R[4][c];
            float l3 = min3f(b, cc, d);
            float m3 = med3f(b, cc, d);
            float h3 = max3f(b, cc, d);
            T0[c] = fminf(l3, e);
            T1[c] = med3f(l3, m3, e);
            T2[c] = med3f(m3, h3, e);
            T3[c] = fmaxf(h3, e);
        }
        float med0[4] = {0.f, 0.f, 0.f, 0.f};
        float med1[4] = {0.f, 0.f, 0.f, 0.f};
        if ((unsigned)m0 < HH) {          // window m0: insert row m0-2 (R0)
            float S0[8], S1[8], S2[8], S3[8], S4[8];
            #pragma unroll
            for (int c = 0; c < 8; ++c) {
                float a = R[0][c];
                S0[c] = fminf(T0[c], a);
                S1[c] = med3f(T0[c], T1[c], a);
                S2[c] = med3f(T1[c], T2[c], a);
                S3[c] = med3f(T2[c], T3[c], a);
                S4[c] = fmaxf(T3[c], a);
            }
            med4net(S0, S1, S2, S3, S4, med0);
        }
        if ((unsigned)(m0 + 1) < HH) {    // window m0+1: insert row m0+3 (R5)
            float S0[8], S1[8], S2[8], S3[8], S4[8];
            #pragma unroll
            for (int c = 0; c < 8; ++c) {
                float f = R[5][c];
                S0[c] = fminf(T0[c], f);
                S1[c] = med3f(T0[c], T1[c], f);
                S2[c] = med3f(T1[c], T2[c], f);
                S3[c] = med3f(T2[c], T3[c], f);
                S4[c] = fmaxf(T3[c], f);
            }
            med4net(S0, S1, S2, S3, S4, med1);
        }
        // horizontal gauss on both med rows; x-halo via shuffles, image-edge -> 0
        float hn0[4], hn1[4];
        {
            float ml0 = __shfl_up(med0[2], 1);
            float ml1 = __shfl_up(med0[3], 1);
            float mr0 = __shfl_down(med0[0], 1);
            float mr1 = __shfl_down(med0[1], 1);
            if (lrefl) { ml0 = 0.f; ml1 = 0.f; }
            if (rrefl) { mr0 = 0.f; mr1 = 0.f; }
            const float hh[8] = { ml0, ml1, med0[0], med0[1], med0[2], med0[3], mr0, mr1 };
            #pragma unroll
            for (int j = 0; j < 4; ++j) {
                float h = 0.f;
                #pragma unroll
                for (int c = 0; c < 5; ++c) h = fmaf(wv[c], hh[j + c], h);
                hn0[j] = h;
            }
        }
        {
            float ml0 = __shfl_up(med1[2], 1);
            float ml1 = __shfl_up(med1[3], 1);
            float mr0 = __shfl_down(med1[0], 1);
            float mr1 = __shfl_down(med1[1], 1);
            if (lrefl) { ml0 = 0.f; ml1 = 0.f; }
            if (rrefl) { mr0 = 0.f; mr1 = 0.f; }
            const float hh[8] = { ml0, ml1, med1[0], med1[1], med1[2], med1[3], mr0, mr1 };
            #pragma unroll
            for (int j = 0; j < 4; ++j) {
                float h = 0.f;
                #pragma unroll
                for (int c = 0; c < 5; ++c) h = fmaf(wv[c], hh[j + c], h);
                hn1[j] = h;
            }
        }
        // vertical gauss + stores: out rows o0 = m0-2, o1 = m0-1
        if (it >= 2) {
            float a0[4], a1[4];
            #pragma unroll
            for (int j = 0; j < 4; ++j) {
                a0[j] = wv[0] * hr[0][j] + wv[1] * hr[1][j] + wv[2] * hr[2][j]
                      + wv[3] * hr[3][j] + wv[4] * hn0[j];
                a1[j] = wv[0] * hr[1][j] + wv[1] * hr[2][j] + wv[2] * hr[3][j]
                      + wv[3] * hn0[j]  + wv[4] * hn1[j];
            }
            if (dostore) {
                const int o0 = m0 - 2;
                *reinterpret_cast<float4*>(obase + (size_t)o0 * WW + x0) =
                    make_float4(a0[0], a0[1], a0[2], a0[3]);
                *reinterpret_cast<float4*>(obase + (size_t)(o0 + 1) * WW + x0) =
                    make_float4(a1[0], a1[1], a1[2], a1[3]);
            }
        }
        // register shifts (keep all indices static across the rolled loop)
        #pragma unroll
        for (int j = 0; j < 4; ++j) {
            hr[0][j] = hr[2][j];
            hr[1][j] = hr[3][j];
            hr[2][j] = hn0[j];
            hr[3][j] = hn1[j];
        }
        #pragma unroll
        for (int k = 0; k < 6; ++k)
            #pragma unroll
            for (int c = 0; c < 8; ++c) R[k][c] = R[k + 2][c];
    }
}

extern "C" void kernel_launch(void* const* d_in, const int* in_sizes, int n_in,
                              void* d_out, int out_size, void* d_ws, size_t ws_size,
                              hipStream_t stream) {
    const float* img = (const float*)d_in[0];
    const float* sig = (const float*)d_in[1];
    float* out = (float*)d_out;

    dim3 grid(NIMG * 5 * (HH / TROWS));  // 2560 one-wave blocks, XCD-affine via bid&7
    dim3 block(64);
    hipLaunchKernelGGL(fused_kernel, grid, block, 0, stream, img, sig, out);
}

// Round 13
// 37.614 us; speedup vs baseline: 1.5215x; 1.5215x over previous
//
#include <hip/hip_runtime.h>

#define HH 1024
#define WW 1024
#define NIMG 8
#define TROWS 16            // output rows per block
#define NSTEP (TROWS + 4)   // 20 median rows per block (incl. +/-2 halo)

__device__ __forceinline__ float med3f(float a, float b, float c) {
    return __builtin_amdgcn_fmed3f(a, b, c);
}
__device__ __forceinline__ float min3f(float a, float b, float c) {
    return fminf(fminf(a, b), c);
}
__device__ __forceinline__ float max3f(float a, float b, float c) {
    return fmaxf(fmaxf(a, b), c);
}

// ranks 3,4 of 5
__device__ __forceinline__ void top2(float a, float b, float c, float d, float e,
                                     float& r3, float& r4) {
    float m3 = med3f(a, b, c);
    float h3 = max3f(a, b, c);
    float s2 = med3f(m3, h3, d);
    float s3 = fmaxf(h3, d);
    r3 = med3f(s2, s3, e);
    r4 = fmaxf(s3, e);
}
// ranks 0,1 of 5
__device__ __forceinline__ void bot2(float a, float b, float c, float d, float e,
                                     float& r0, float& r1) {
    float l3 = min3f(a, b, c);
    float m3 = med3f(a, b, c);
    float s0 = fminf(l3, d);
    float s1 = med3f(l3, m3, d);
    r0 = fminf(s0, e);
    r1 = med3f(s0, s1, e);
}
// ranks 2,3,4 of 5
__device__ __forceinline__ void top3(float a, float b, float c, float d, float e,
                                     float& r2, float& r3, float& r4) {
    float l3 = min3f(a, b, c);
    float m3 = med3f(a, b, c);
    float h3 = max3f(a, b, c);
    float s1 = med3f(l3, m3, d);
    float s2 = med3f(m3, h3, d);
    float s3 = fmaxf(h3, d);
    r2 = med3f(s1, s2, e);
    r3 = med3f(s2, s3, e);
    r4 = fmaxf(s3, e);
}
// ranks 0,1,2 of 5
__device__ __forceinline__ void bot3(float a, float b, float c, float d, float e,
                                     float& r0, float& r1, float& r2) {
    float l3 = min3f(a, b, c);
    float m3 = med3f(a, b, c);
    float h3 = max3f(a, b, c);
    float s0 = fminf(l3, d);
    float s1 = med3f(l3, m3, d);
    float s2 = med3f(m3, h3, d);
    r0 = fminf(s0, e);
    r1 = med3f(s0, s1, e);
    r2 = med3f(s1, s2, e);
}
// ranks 1,2,3 of 5
__device__ __forceinline__ void mid3(float a, float b, float c, float d, float e,
                                     float& r1, float& r2, float& r3) {
    float l3 = min3f(a, b, c);
    float m3 = med3f(a, b, c);
    float h3 = max3f(a, b, c);
    float s0 = fminf(l3, d);
    float s1 = med3f(l3, m3, d);
    float s2 = med3f(m3, h3, d);
    float s3 = fmaxf(h3, d);
    r1 = med3f(s0, s1, e);
    r2 = med3f(s1, s2, e);
    r3 = med3f(s2, s3, e);
}

// load one reflect-padded input row (x handled branchlessly per-lane)
__device__ __forceinline__ void loadrow(const float* __restrict__ base, int r,
                                        int tid, int x0, float (&d)[8]) {
    const int rr = (r < 0) ? -r : (r >= HH ? 2 * HH - 2 - r : r);
    const float* rp = base + (size_t)rr * WW;
    const float4 A = *reinterpret_cast<const float4*>(rp + (tid == 0   ? x0 : x0 - 4));
    const float4 B = *reinterpret_cast<const float4*>(rp + x0);
    const float4 C = *reinterpret_cast<const float4*>(rp + (tid == 255 ? x0 : x0 + 4));
    d[0] = (tid == 0)   ? B.z : A.z;   // reflect(-2)=2, reflect(-1)=1
    d[1] = (tid == 0)   ? B.y : A.w;
    d[2] = B.x; d[3] = B.y; d[4] = B.z; d[5] = B.w;
    d[6] = (tid == 255) ? B.z : C.x;   // reflect(1024)=1022, reflect(1025)=1021
    d[7] = (tid == 255) ? B.y : C.y;
}

// 13-candidate exact median-of-25 network over sorted columns (validated R2-R12)
__device__ __forceinline__ void med4net(const float (&S0)[8], const float (&S1)[8],
                                        const float (&S2)[8], const float (&S3)[8],
                                        const float (&S4)[8], float (&med)[4]) {
    #pragma unroll
    for (int j = 0; j < 4; ++j) {
        float r03, r04, r12, r13, r14, r21, r22, r23, r30, r31, r32, r40, r41;
        top2(S0[j], S0[j+1], S0[j+2], S0[j+3], S0[j+4], r03, r04);
        top3(S1[j], S1[j+1], S1[j+2], S1[j+3], S1[j+4], r12, r13, r14);
        mid3(S2[j], S2[j+1], S2[j+2], S2[j+3], S2[j+4], r21, r22, r23);
        bot3(S3[j], S3[j+1], S3[j+2], S3[j+3], S3[j+4], r30, r31, r32);
        bot2(S4[j], S4[j+1], S4[j+2], S4[j+3], S4[j+4], r40, r41);
        float u = fminf(r40, r31), v = fmaxf(r40, r31);
        float w = fminf(v, r32),  x = fmaxf(v, r32);
        float ps0 = r30, ps1 = u, ps2 = w;
        float ps3 = fminf(x, r41), ps4 = fmaxf(x, r41);
        float q0 = fminf(r21, r03);
        float q1 = med3f(r21, r22, r03);
        float q2 = med3f(r22, r23, r03);
        float t1 = fminf(q1, r04);
        float t2 = med3f(q1, q2, r04);
        float t3 = med3f(q2, r23, r04);
        float t4 = fmaxf(r23, r04);
        float Y0 = fmaxf(ps0, q0);
        float Y1 = fmaxf(ps1, t1);
        float X2 = fminf(ps2, t2), Y2 = fmaxf(ps2, t2);
        float X3 = fminf(ps3, t3);
        float X4 = fminf(ps4, t4);
        float L  = max3f(X2, Y0, r12);
        float M  = med3f(X3, Y1, r13);
        float Hc = min3f(X4, Y2, r14);
        med[j] = med3f(L, M, Hc);
    }
}

// Double-step K (K = 0..10): computes median rows m0 = y0-2+2K and m0+1
// (shared sorted4 of their 4 common rows), lagged LDS x-halo exchange of the
// previous pair, h-gauss on that pair, outputs rows y0-6+2K, +1 for K>=3.
// All ring/hr/LDS indices compile-time. Barrier at end (except last step).
template<int K>
__device__ __forceinline__ void dstep(int y0, int tid, int x0,
                                      const float* __restrict__ base,
                                      float* __restrict__ obase,
                                      const float (&wv)[5],
                                      float (&ring)[8][8], float (&hr)[6][4],
                                      float (*lbuf)[1032]) {
    // 1) lagged LDS pair read: med rows y0-4+2K, y0-3+2K (written at K-1)
    float ha[8], hb[8];
    if constexpr (K >= 1) {
        const float* La = lbuf[2 * ((K + 1) & 1)];
        const float* Lb = lbuf[2 * ((K + 1) & 1) + 1];
        const float4 a0 = *reinterpret_cast<const float4*>(&La[x0]);
        const float4 a1 = *reinterpret_cast<const float4*>(&La[x0 + 4]);
        const float4 b0 = *reinterpret_cast<const float4*>(&Lb[x0]);
        const float4 b1 = *reinterpret_cast<const float4*>(&Lb[x0 + 4]);
        ha[0]=a0.x; ha[1]=a0.y; ha[2]=a0.z; ha[3]=a0.w;
        ha[4]=a1.x; ha[5]=a1.y; ha[6]=a1.z; ha[7]=a1.w;
        hb[0]=b0.x; hb[1]=b0.y; hb[2]=b0.z; hb[3]=b0.w;
        hb[4]=b1.x; hb[5]=b1.y; hb[6]=b1.z; hb[7]=b1.w;
    }
    // 2) prefetch next two input rows
    if constexpr (K <= 8) {
        loadrow(base, y0 + 2 + 2 * K, tid, x0, ring[(2 * K + 6) & 7]);
        loadrow(base, y0 + 3 + 2 * K, tid, x0, ring[(2 * K + 7) & 7]);
    }
    // 3) median pair (shared sorted4 of rows m0-1..m0+2 = slots s1..s4)
    if constexpr (K <= 9) {
        constexpr int s0 = (2*K) & 7,     s1 = (2*K + 1) & 7, s2 = (2*K + 2) & 7;
        constexpr int s3 = (2*K + 3) & 7, s4 = (2*K + 4) & 7, s5 = (2*K + 5) & 7;
        float T0[8], T1[8], T2[8], T3[8];
        #pragma unroll
        for (int c = 0; c < 8; ++c) {
            float b = ring[s1][c], cc = ring[s2][c], d = ring[s3][c], e = ring[s4][c];
            float l3 = min3f(b, cc, d);
            float m3 = med3f(b, cc, d);
            float h3 = max3f(b, cc, d);
            T0[c] = fminf(l3, e);
            T1[c] = med3f(l3, m3, e);
            T2[c] = med3f(m3, h3, e);
            T3[c] = fmaxf(h3, e);
        }
        const int m0 = y0 - 2 + 2 * K;
        float med0[4] = {0.f, 0.f, 0.f, 0.f};
        float med1[4] = {0.f, 0.f, 0.f, 0.f};
        if (m0 >= 0 && m0 < HH) {   // insert row m0-2 (slot s0) -> window m0
            float S0[8], S1[8], S2[8], S3[8], S4[8];
            #pragma unroll
            for (int c = 0; c < 8; ++c) {
                float a = ring[s0][c];
                S0[c] = fminf(T0[c], a);
                S1[c] = med3f(T0[c], T1[c], a);
                S2[c] = med3f(T1[c], T2[c], a);
                S3[c] = med3f(T2[c], T3[c], a);
                S4[c] = fmaxf(T3[c], a);
            }
            med4net(S0, S1, S2, S3, S4, med0);
        }
        const int m1 = m0 + 1;
        if (m1 >= 0 && m1 < HH) {   // insert row m1+2 (slot s5) -> window m1
            float S0[8], S1[8], S2[8], S3[8], S4[8];
            #pragma unroll
            for (int c = 0; c < 8; ++c) {
                float f = ring[s5][c];
                S0[c] = fminf(T0[c], f);
                S1[c] = med3f(T0[c], T1[c], f);
                S2[c] = med3f(T1[c], T2[c], f);
                S3[c] = med3f(T2[c], T3[c], f);
                S4[c] = fmaxf(T3[c], f);
            }
            med4net(S0, S1, S2, S3, S4, med1);
        }
        float* Lw0 = lbuf[2 * (K & 1)];
        float* Lw1 = lbuf[2 * (K & 1) + 1];
        *reinterpret_cast<float2*>(&Lw0[x0 + 2]) = make_float2(med0[0], med0[1]);
        *reinterpret_cast<float2*>(&Lw0[x0 + 4]) = make_float2(med0[2], med0[3]);
        *reinterpret_cast<float2*>(&Lw1[x0 + 2]) = make_float2(med1[0], med1[1]);
        *reinterpret_cast<float2*>(&Lw1[x0 + 4]) = make_float2(med1[2], med1[3]);
    }
    // 4) horizontal gauss on the lagged pair -> hr slots (2K)%6, (2K+1)%6
    if constexpr (K >= 1) {
        #pragma unroll
        for (int j = 0; j < 4; ++j) {
            float h = 0.f;
            #pragma unroll
            for (int c = 0; c < 5; ++c) h = fmaf(wv[c], ha[j + c], h);
            hr[(2 * K) % 6][j] = h;
        }
        #pragma unroll
        for (int j = 0; j < 4; ++j) {
            float h = 0.f;
            #pragma unroll
            for (int c = 0; c < 5; ++c) h = fmaf(wv[c], hb[j + c], h);
            hr[(2 * K + 1) % 6][j] = h;
        }
    }
    // 5) vertical gauss + store output rows o0 = y0-6+2K, o1 = o0+1
    if constexpr (K >= 3) {
        {
            float a0 = 0.f, a1 = 0.f, a2 = 0.f, a3 = 0.f;
            #pragma unroll
            for (int k = 0; k < 5; ++k) {
                const int   sl = (2 * K - 4 + k) % 6;
                const float wy = wv[k];
                a0 = fmaf(wy, hr[sl][0], a0);
                a1 = fmaf(wy, hr[sl][1], a1);
                a2 = fmaf(wy, hr[sl][2], a2);
                a3 = fmaf(wy, hr[sl][3], a3);
            }
            const int o0 = y0 - 6 + 2 * K;
            *reinterpret_cast<float4*>(obase + (size_t)o0 * WW + x0) =
                make_float4(a0, a1, a2, a3);
        }
        {
            float a0 = 0.f, a1 = 0.f, a2 = 0.f, a3 = 0.f;
            #pragma unroll
            for (int k = 0; k < 5; ++k) {
                const int   sl = (2 * K - 3 + k) % 6;
                const float wy = wv[k];
                a0 = fmaf(wy, hr[sl][0], a0);
                a1 = fmaf(wy, hr[sl][1], a1);
                a2 = fmaf(wy, hr[sl][2], a2);
                a3 = fmaf(wy, hr[sl][3], a3);
            }
            const int o1 = y0 - 5 + 2 * K;
            *reinterpret_cast<float4*>(obase + (size_t)o1 * WW + x0) =
                make_float4(a0, a1, a2, a3);
        }
    }
    if constexpr (K < 10) __syncthreads();
}

// Fused median(reflect) + gaussian(zero-pad). Block = 16 rows x 1024 px.
// img = bid & 7 -> XCD-affine. 512 blocks; 10 barriers/block.
__global__ __launch_bounds__(256, 2) void fused_kernel(const float* __restrict__ in,
                                                       const float* __restrict__ sig,
                                                       float* __restrict__ out) {
    const int bi   = blockIdx.x;
    const int img  = bi & 7;
    const int tile = bi >> 3;
    const int y0   = tile * TROWS;
    const int tid  = threadIdx.x;
    const int x0   = tid * 4;
    const float* base  = in  + (size_t)img * HH * WW;
    float*       obase = out + (size_t)img * HH * WW;

    const float sigma  = sig[0];
    const float inv2s2 = 1.0f / (2.0f * sigma * sigma);
    const float g1 = expf(-1.0f * inv2s2);
    const float g4 = expf(-4.0f * inv2s2);
    const float sn = 1.0f + 2.0f * g1 + 2.0f * g4;
    const float wv[5] = { g4 / sn, g1 / sn, 1.0f / sn, g1 / sn, g4 / sn };

    // 2 double-buffered PAIRS of exchange rows; [0,1] and [1026,1027] are
    // zero borders (x zero-pad); stride 1032 keeps rows 16B-aligned.
    __shared__ float lbuf[4][1032];
    if (tid < 8) {
        const int r = tid >> 1, p = tid & 1;
        lbuf[r][p] = 0.f;
        lbuf[r][1026 + p] = 0.f;
    }

    float ring[8][8];   // raw input rows; row r <-> slot (r - y0 + 4) & 7
    float hr[6][4];     // h-blurred med rows; med row m <-> slot (m - y0 + 4) % 6

    #pragma unroll
    for (int k = 0; k < 6; ++k) loadrow(base, y0 - 4 + k, tid, x0, ring[k]);

    dstep<0>(y0, tid, x0, base, obase, wv, ring, hr, lbuf);
    dstep<1>(y0, tid, x0, base, obase, wv, ring, hr, lbuf);
    dstep<2>(y0, tid, x0, base, obase, wv, ring, hr, lbuf);
    dstep<3>(y0, tid, x0, base, obase, wv, ring, hr, lbuf);
    dstep<4>(y0, tid, x0, base, obase, wv, ring, hr, lbuf);
    dstep<5>(y0, tid, x0, base, obase, wv, ring, hr, lbuf);
    dstep<6>(y0, tid, x0, base, obase, wv, ring, hr, lbuf);
    dstep<7>(y0, tid, x0, base, obase, wv, ring, hr, lbuf);
    dstep<8>(y0, tid, x0, base, obase, wv, ring, hr, lbuf);
    dstep<9>(y0, tid, x0, base, obase, wv, ring, hr, lbuf);
    dstep<10>(y0, tid, x0, base, obase, wv, ring, hr, lbuf);
}

extern "C" void kernel_launch(void* const* d_in, const int* in_sizes, int n_in,
                              void* d_out, int out_size, void* d_ws, size_t ws_size,
                              hipStream_t stream) {
    const float* img = (const float*)d_in[0];
    const float* sig = (const float*)d_in[1];
    float* out = (float*)d_out;

    dim3 grid(NIMG * (HH / TROWS));  // 512 blocks, XCD-affine via bid&7
    dim3 block(256);
    hipLaunchKernelGGL(fused_kernel, grid, block, 0, stream, img, sig, out);
}

// Round 14
// 33.472 us; speedup vs baseline: 1.7098x; 1.1238x over previous
//
#include <hip/hip_runtime.h>

#define HH 1024
#define WW 1024
#define NIMG 8
#define TROWS 16            // output rows per block
#define NSTEP (TROWS + 4)   // 20 median rows per block (incl. +/-2 halo)

__device__ __forceinline__ float med3f(float a, float b, float c) {
    return __builtin_amdgcn_fmed3f(a, b, c);
}
__device__ __forceinline__ float min3f(float a, float b, float c) {
    return fminf(fminf(a, b), c);
}
__device__ __forceinline__ float max3f(float a, float b, float c) {
    return fmaxf(fmaxf(a, b), c);
}

// load one reflect-padded input row (x handled branchlessly per-lane)
__device__ __forceinline__ void loadrow(const float* __restrict__ base, int r,
                                        int tid, int x0, float (&d)[8]) {
    const int rr = (r < 0) ? -r : (r >= HH ? 2 * HH - 2 - r : r);
    const float* rp = base + (size_t)rr * WW;
    const float4 A = *reinterpret_cast<const float4*>(rp + (tid == 0   ? x0 : x0 - 4));
    const float4 B = *reinterpret_cast<const float4*>(rp + x0);
    const float4 C = *reinterpret_cast<const float4*>(rp + (tid == 255 ? x0 : x0 + 4));
    d[0] = (tid == 0)   ? B.z : A.z;   // reflect(-2)=2, reflect(-1)=1
    d[1] = (tid == 0)   ? B.y : A.w;
    d[2] = B.x; d[3] = B.y; d[4] = B.z; d[5] = B.w;
    d[6] = (tid == 255) ? B.z : C.x;   // reflect(1024)=1022, reflect(1025)=1021
    d[7] = (tid == 255) ? B.y : C.y;
}

// Rank stage with x-shared sorted4: windows (0,1) share sorted4(S[1..4]),
// windows (2,3) share sorted4(S[3..6]); per-window ranks via the validated
// sorted4+insert identities (r0=min(T0,a), r1=med3(T0,T1,a), r2=med3(T1,T2,a),
// r3=med3(T2,T3,a), r4=max(T3,a)), with unused sorted4 outputs omitted.
// Then the validated 13-candidate merge per window. Exact.
__device__ __forceinline__ void med4net8(const float (&S0)[8], const float (&S1)[8],
                                         const float (&S2)[8], const float (&S3)[8],
                                         const float (&S4)[8], float (&med)[4]) {
    float r03[4], r04[4], r12[4], r13[4], r14[4];
    float r21[4], r22[4], r23[4], r30[4], r31[4], r32[4], r40[4], r41[4];

    // ---- ROW 0 (S0): need ranks 3,4 (top part of sorted4 only) ----
    {
        float m3 = med3f(S0[1], S0[2], S0[3]);
        float h3 = max3f(S0[1], S0[2], S0[3]);
        float T2 = med3f(m3, h3, S0[4]);
        float T3 = fmaxf(h3, S0[4]);
        r03[0] = med3f(T2, T3, S0[0]);  r04[0] = fmaxf(T3, S0[0]);
        r03[1] = med3f(T2, T3, S0[5]);  r04[1] = fmaxf(T3, S0[5]);
        float m3b = med3f(S0[3], S0[4], S0[5]);
        float h3b = max3f(S0[3], S0[4], S0[5]);
        float U2 = med3f(m3b, h3b, S0[6]);
        float U3 = fmaxf(h3b, S0[6]);
        r03[2] = med3f(U2, U3, S0[2]);  r04[2] = fmaxf(U3, S0[2]);
        r03[3] = med3f(U2, U3, S0[7]);  r04[3] = fmaxf(U3, S0[7]);
    }
    // ---- ROW 1 (S1): need ranks 2,3,4 (T1,T2,T3) ----
    {
        float l3 = min3f(S1[1], S1[2], S1[3]);
        float m3 = med3f(S1[1], S1[2], S1[3]);
        float h3 = max3f(S1[1], S1[2], S1[3]);
        float T1 = med3f(l3, m3, S1[4]);
        float T2 = med3f(m3, h3, S1[4]);
        float T3 = fmaxf(h3, S1[4]);
        r12[0] = med3f(T1, T2, S1[0]); r13[0] = med3f(T2, T3, S1[0]); r14[0] = fmaxf(T3, S1[0]);
        r12[1] = med3f(T1, T2, S1[5]); r13[1] = med3f(T2, T3, S1[5]); r14[1] = fmaxf(T3, S1[5]);
        float l3b = min3f(S1[3], S1[4], S1[5]);
        float m3b = med3f(S1[3], S1[4], S1[5]);
        float h3b = max3f(S1[3], S1[4], S1[5]);
        float U1 = med3f(l3b, m3b, S1[6]);
        float U2 = med3f(m3b, h3b, S1[6]);
        float U3 = fmaxf(h3b, S1[6]);
        r12[2] = med3f(U1, U2, S1[2]); r13[2] = med3f(U2, U3, S1[2]); r14[2] = fmaxf(U3, S1[2]);
        r12[3] = med3f(U1, U2, S1[7]); r13[3] = med3f(U2, U3, S1[7]); r14[3] = fmaxf(U3, S1[7]);
    }
    // ---- ROW 2 (S2): need ranks 1,2,3 (full sorted4) ----
    {
        float l3 = min3f(S2[1], S2[2], S2[3]);
        float m3 = med3f(S2[1], S2[2], S2[3]);
        float h3 = max3f(S2[1], S2[2], S2[3]);
        float T0 = fminf(l3, S2[4]);
        float T1 = med3f(l3, m3, S2[4]);
        float T2 = med3f(m3, h3, S2[4]);
        float T3 = fmaxf(h3, S2[4]);
        r21[0] = med3f(T0, T1, S2[0]); r22[0] = med3f(T1, T2, S2[0]); r23[0] = med3f(T2, T3, S2[0]);
        r21[1] = med3f(T0, T1, S2[5]); r22[1] = med3f(T1, T2, S2[5]); r23[1] = med3f(T2, T3, S2[5]);
        float l3b = min3f(S2[3], S2[4], S2[5]);
        float m3b = med3f(S2[3], S2[4], S2[5]);
        float h3b = max3f(S2[3], S2[4], S2[5]);
        float U0 = fminf(l3b, S2[6]);
        float U1 = med3f(l3b, m3b, S2[6]);
        float U2 = med3f(m3b, h3b, S2[6]);
        float U3 = fmaxf(h3b, S2[6]);
        r21[2] = med3f(U0, U1, S2[2]); r22[2] = med3f(U1, U2, S2[2]); r23[2] = med3f(U2, U3, S2[2]);
        r21[3] = med3f(U0, U1, S2[7]); r22[3] = med3f(U1, U2, S2[7]); r23[3] = med3f(U2, U3, S2[7]);
    }
    // ---- ROW 3 (S3): need ranks 0,1,2 (T0,T1,T2) ----
    {
        float l3 = min3f(S3[1], S3[2], S3[3]);
        float m3 = med3f(S3[1], S3[2], S3[3]);
        float h3 = max3f(S3[1], S3[2], S3[3]);
        float T0 = fminf(l3, S3[4]);
        float T1 = med3f(l3, m3, S3[4]);
        float T2 = med3f(m3, h3, S3[4]);
        r30[0] = fminf(T0, S3[0]); r31[0] = med3f(T0, T1, S3[0]); r32[0] = med3f(T1, T2, S3[0]);
        r30[1] = fminf(T0, S3[5]); r31[1] = med3f(T0, T1, S3[5]); r32[1] = med3f(T1, T2, S3[5]);
        float l3b = min3f(S3[3], S3[4], S3[5]);
        float m3b = med3f(S3[3], S3[4], S3[5]);
        float h3b = max3f(S3[3], S3[4], S3[5]);
        float U0 = fminf(l3b, S3[6]);
        float U1 = med3f(l3b, m3b, S3[6]);
        float U2 = med3f(m3b, h3b, S3[6]);
        r30[2] = fminf(U0, S3[2]); r31[2] = med3f(U0, U1, S3[2]); r32[2] = med3f(U1, U2, S3[2]);
        r30[3] = fminf(U0, S3[7]); r31[3] = med3f(U0, U1, S3[7]); r32[3] = med3f(U1, U2, S3[7]);
    }
    // ---- ROW 4 (S4): need ranks 0,1 (bottom part only) ----
    {
        float l3 = min3f(S4[1], S4[2], S4[3]);
        float m3 = med3f(S4[1], S4[2], S4[3]);
        float T0 = fminf(l3, S4[4]);
        float T1 = med3f(l3, m3, S4[4]);
        r40[0] = fminf(T0, S4[0]); r41[0] = med3f(T0, T1, S4[0]);
        r40[1] = fminf(T0, S4[5]); r41[1] = med3f(T0, T1, S4[5]);
        float l3b = min3f(S4[3], S4[4], S4[5]);
        float m3b = med3f(S4[3], S4[4], S4[5]);
        float U0 = fminf(l3b, S4[6]);
        float U1 = med3f(l3b, m3b, S4[6]);
        r40[2] = fminf(U0, S4[2]); r41[2] = med3f(U0, U1, S4[2]);
        r40[3] = fminf(U0, S4[7]); r41[3] = med3f(U0, U1, S4[7]);
    }
    // ---- merge stage per window (validated R2-R13, unchanged) ----
    #pragma unroll
    for (int j = 0; j < 4; ++j) {
        float u = fminf(r40[j], r31[j]), v = fmaxf(r40[j], r31[j]);
        float w = fminf(v, r32[j]),  x = fmaxf(v, r32[j]);
        float ps0 = r30[j], ps1 = u, ps2 = w;
        float ps3 = fminf(x, r41[j]), ps4 = fmaxf(x, r41[j]);
        float q0 = fminf(r21[j], r03[j]);
        float q1 = med3f(r21[j], r22[j], r03[j]);
        float q2 = med3f(r22[j], r23[j], r03[j]);
        float t1 = fminf(q1, r04[j]);
        float t2 = med3f(q1, q2, r04[j]);
        float t3 = med3f(q2, r23[j], r04[j]);
        float t4 = fmaxf(r23[j], r04[j]);
        float Y0 = fmaxf(ps0, q0);
        float Y1 = fmaxf(ps1, t1);
        float X2 = fminf(ps2, t2), Y2 = fmaxf(ps2, t2);
        float X3 = fminf(ps3, t3);
        float X4 = fminf(ps4, t4);
        float L  = max3f(X2, Y0, r12[j]);
        float M  = med3f(X3, Y1, r13[j]);
        float Hc = min3f(X4, Y2, r14[j]);
        med[j] = med3f(L, M, Hc);
    }
}

// Double-step K (K = 0..10): median rows m0 = y0-2+2K, m0+1 via shared sorted4
// in y (column stage) and shared sorted4 in x (rank stage, med4net8).
// Lagged LDS x-halo exchange of the previous pair, h-gauss on that pair,
// outputs rows y0-6+2K, +1 for K>=3. All indices compile-time.
template<int K>
__device__ __forceinline__ void dstep(int y0, int tid, int x0,
                                      const float* __restrict__ base,
                                      float* __restrict__ obase,
                                      const float (&wv)[5],
                                      float (&ring)[8][8], float (&hr)[6][4],
                                      float (*lbuf)[1032]) {
    // 1) lagged LDS pair read: med rows y0-4+2K, y0-3+2K (written at K-1)
    float ha[8], hb[8];
    if constexpr (K >= 1) {
        const float* La = lbuf[2 * ((K + 1) & 1)];
        const float* Lb = lbuf[2 * ((K + 1) & 1) + 1];
        const float4 a0 = *reinterpret_cast<const float4*>(&La[x0]);
        const float4 a1 = *reinterpret_cast<const float4*>(&La[x0 + 4]);
        const float4 b0 = *reinterpret_cast<const float4*>(&Lb[x0]);
        const float4 b1 = *reinterpret_cast<const float4*>(&Lb[x0 + 4]);
        ha[0]=a0.x; ha[1]=a0.y; ha[2]=a0.z; ha[3]=a0.w;
        ha[4]=a1.x; ha[5]=a1.y; ha[6]=a1.z; ha[7]=a1.w;
        hb[0]=b0.x; hb[1]=b0.y; hb[2]=b0.z; hb[3]=b0.w;
        hb[4]=b1.x; hb[5]=b1.y; hb[6]=b1.z; hb[7]=b1.w;
    }
    // 2) prefetch next two input rows
    if constexpr (K <= 8) {
        loadrow(base, y0 + 2 + 2 * K, tid, x0, ring[(2 * K + 6) & 7]);
        loadrow(base, y0 + 3 + 2 * K, tid, x0, ring[(2 * K + 7) & 7]);
    }
    // 3) median pair (shared sorted4 of rows m0-1..m0+2 = slots s1..s4)
    if constexpr (K <= 9) {
        constexpr int s0 = (2*K) & 7,     s1 = (2*K + 1) & 7, s2 = (2*K + 2) & 7;
        constexpr int s3 = (2*K + 3) & 7, s4 = (2*K + 4) & 7, s5 = (2*K + 5) & 7;
        float T0[8], T1[8], T2[8], T3[8];
        #pragma unroll
        for (int c = 0; c < 8; ++c) {
            float b = ring[s1][c], cc = ring[s2][c], d = ring[s3][c], e = ring[s4][c];
            float l3 = min3f(b, cc, d);
            float m3 = med3f(b, cc, d);
            float h3 = max3f(b, cc, d);
            T0[c] = fminf(l3, e);
            T1[c] = med3f(l3, m3, e);
            T2[c] = med3f(m3, h3, e);
            T3[c] = fmaxf(h3, e);
        }
        const int m0 = y0 - 2 + 2 * K;
        float med0[4] = {0.f, 0.f, 0.f, 0.f};
        float med1[4] = {0.f, 0.f, 0.f, 0.f};
        if (m0 >= 0 && m0 < HH) {   // insert row m0-2 (slot s0) -> window m0
            float S0[8], S1[8], S2[8], S3[8], S4[8];
            #pragma unroll
            for (int c = 0; c < 8; ++c) {
                float a = ring[s0][c];
                S0[c] = fminf(T0[c], a);
                S1[c] = med3f(T0[c], T1[c], a);
                S2[c] = med3f(T1[c], T2[c], a);
                S3[c] = med3f(T2[c], T3[c], a);
                S4[c] = fmaxf(T3[c], a);
            }
            med4net8(S0, S1, S2, S3, S4, med0);
        }
        const int m1 = m0 + 1;
        if (m1 >= 0 && m1 < HH) {   // insert row m1+2 (slot s5) -> window m1
            float S0[8], S1[8], S2[8], S3[8], S4[8];
            #pragma unroll
            for (int c = 0; c < 8; ++c) {
                float f = ring[s5][c];
                S0[c] = fminf(T0[c], f);
                S1[c] = med3f(T0[c], T1[c], f);
                S2[c] = med3f(T1[c], T2[c], f);
                S3[c] = med3f(T2[c], T3[c], f);
                S4[c] = fmaxf(T3[c], f);
            }
            med4net8(S0, S1, S2, S3, S4, med1);
        }
        float* Lw0 = lbuf[2 * (K & 1)];
        float* Lw1 = lbuf[2 * (K & 1) + 1];
        *reinterpret_cast<float2*>(&Lw0[x0 + 2]) = make_float2(med0[0], med0[1]);
        *reinterpret_cast<float2*>(&Lw0[x0 + 4]) = make_float2(med0[2], med0[3]);
        *reinterpret_cast<float2*>(&Lw1[x0 + 2]) = make_float2(med1[0], med1[1]);
        *reinterpret_cast<float2*>(&Lw1[x0 + 4]) = make_float2(med1[2], med1[3]);
    }
    // 4) horizontal gauss on the lagged pair -> hr slots (2K)%6, (2K+1)%6
    if constexpr (K >= 1) {
        #pragma unroll
        for (int j = 0; j < 4; ++j) {
            float h = 0.f;
            #pragma unroll
            for (int c = 0; c < 5; ++c) h = fmaf(wv[c], ha[j + c], h);
            hr[(2 * K) % 6][j] = h;
        }
        #pragma unroll
        for (int j = 0; j < 4; ++j) {
            float h = 0.f;
            #pragma unroll
            for (int c = 0; c < 5; ++c) h = fmaf(wv[c], hb[j + c], h);
            hr[(2 * K + 1) % 6][j] = h;
        }
    }
    // 5) vertical gauss + store output rows o0 = y0-6+2K, o1 = o0+1
    if constexpr (K >= 3) {
        {
            float a0 = 0.f, a1 = 0.f, a2 = 0.f, a3 = 0.f;
            #pragma unroll
            for (int k = 0; k < 5; ++k) {
                const int   sl = (2 * K - 4 + k) % 6;
                const float wy = wv[k];
                a0 = fmaf(wy, hr[sl][0], a0);
                a1 = fmaf(wy, hr[sl][1], a1);
                a2 = fmaf(wy, hr[sl][2], a2);
                a3 = fmaf(wy, hr[sl][3], a3);
            }
            const int o0 = y0 - 6 + 2 * K;
            *reinterpret_cast<float4*>(obase + (size_t)o0 * WW + x0) =
                make_float4(a0, a1, a2, a3);
        }
        {
            float a0 = 0.f, a1 = 0.f, a2 = 0.f, a3 = 0.f;
            #pragma unroll
            for (int k = 0; k < 5; ++k) {
                const int   sl = (2 * K - 3 + k) % 6;
                const float wy = wv[k];
                a0 = fmaf(wy, hr[sl][0], a0);
                a1 = fmaf(wy, hr[sl][1], a1);
                a2 = fmaf(wy, hr[sl][2], a2);
                a3 = fmaf(wy, hr[sl][3], a3);
            }
            const int o1 = y0 - 5 + 2 * K;
            *reinterpret_cast<float4*>(obase + (size_t)o1 * WW + x0) =
                make_float4(a0, a1, a2, a3);
        }
    }
    if constexpr (K < 10) __syncthreads();
}

// Fused median(reflect) + gaussian(zero-pad). Block = 16 rows x 1024 px.
// img = bid & 7 -> XCD-affine. 512 blocks; 10 barriers/block.
__global__ __launch_bounds__(256, 2) void fused_kernel(const float* __restrict__ in,
                                                       const float* __restrict__ sig,
                                                       float* __restrict__ out) {
    const int bi   = blockIdx.x;
    const int img  = bi & 7;
    const int tile = bi >> 3;
    const int y0   = tile * TROWS;
    const int tid  = threadIdx.x;
    const int x0   = tid * 4;
    const float* base  = in  + (size_t)img * HH * WW;
    float*       obase = out + (size_t)img * HH * WW;

    const float sigma  = sig[0];
    const float inv2s2 = 1.0f / (2.0f * sigma * sigma);
    const float g1 = expf(-1.0f * inv2s2);
    const float g4 = expf(-4.0f * inv2s2);
    const float sn = 1.0f + 2.0f * g1 + 2.0f * g4;
    const float wv[5] = { g4 / sn, g1 / sn, 1.0f / sn, g1 / sn, g4 / sn };

    // 2 double-buffered PAIRS of exchange rows; [0,1] and [1026,1027] are
    // zero borders (x zero-pad); stride 1032 keeps rows 16B-aligned.
    __shared__ float lbuf[4][1032];
    if (tid < 8) {
        const int r = tid >> 1, p = tid & 1;
        lbuf[r][p] = 0.f;
        lbuf[r][1026 + p] = 0.f;
    }

    float ring[8][8];   // raw input rows; row r <-> slot (r - y0 + 4) & 7
    float hr[6][4];     // h-blurred med rows; med row m <-> slot (m - y0 + 4) % 6

    #pragma unroll
    for (int k = 0; k < 6; ++k) loadrow(base, y0 - 4 + k, tid, x0, ring[k]);

    dstep<0>(y0, tid, x0, base, obase, wv, ring, hr, lbuf);
    dstep<1>(y0, tid, x0, base, obase, wv, ring, hr, lbuf);
    dstep<2>(y0, tid, x0, base, obase, wv, ring, hr, lbuf);
    dstep<3>(y0, tid, x0, base, obase, wv, ring, hr, lbuf);
    dstep<4>(y0, tid, x0, base, obase, wv, ring, hr, lbuf);
    dstep<5>(y0, tid, x0, base, obase, wv, ring, hr, lbuf);
    dstep<6>(y0, tid, x0, base, obase, wv, ring, hr, lbuf);
    dstep<7>(y0, tid, x0, base, obase, wv, ring, hr, lbuf);
    dstep<8>(y0, tid, x0, base, obase, wv, ring, hr, lbuf);
    dstep<9>(y0, tid, x0, base, obase, wv, ring, hr, lbuf);
    dstep<10>(y0, tid, x0, base, obase, wv, ring, hr, lbuf);
}

extern "C" void kernel_launch(void* const* d_in, const int* in_sizes, int n_in,
                              void* d_out, int out_size, void* d_ws, size_t ws_size,
                              hipStream_t stream) {
    const float* img = (const float*)d_in[0];
    const float* sig = (const float*)d_in[1];
    float* out = (float*)d_out;

    dim3 grid(NIMG * (HH / TROWS));  // 512 blocks, XCD-affine via bid&7
    dim3 block(256);
    hipLaunchKernelGGL(fused_kernel, grid, block, 0, stream, img, sig, out);
}